// Round 1
// baseline (4744.000 us; speedup 1.0000x reference)
//
#include <hip/hip_runtime.h>

#define N_NODES 50000
#define N_EDGES 800000
#define HD 128
#define NGRAPH 64
#define NOUT 8

// ---------------- degree / dinv ----------------
__global__ __launch_bounds__(256) void deg_k(const int* __restrict__ dst, float* __restrict__ deg) {
    int e = blockIdx.x * 256 + threadIdx.x;
    if (e < N_EDGES) atomicAdd(&deg[dst[e]], 1.0f);
}

__global__ __launch_bounds__(256) void dinv_k(float* __restrict__ deg) {
    int i = blockIdx.x * 256 + threadIdx.x;
    if (i < N_NODES) deg[i] = 1.0f / sqrtf(deg[i] + 1.0f);
}

// ---------------- matmul: Y[nrows,128] = X[nrows,128] @ W[128,128] ----------------
// Block: 256 threads, 64 rows x 128 cols per block. K staged in panels of 32.
__global__ __launch_bounds__(256) void matmul_k(const float* __restrict__ X,
                                                const float* __restrict__ W,
                                                float* __restrict__ Y,
                                                int nrows) {
    __shared__ float XsT[32][68];   // [kk][row], pad 68 keeps float4 alignment (272B = 17*16B)
    __shared__ float Ws[32][128];
    const int t = threadIdx.x;
    const int c8 = (t & 15) * 8;
    const int r4 = (t >> 4) * 4;
    const int row0 = blockIdx.x * 64;

    float acc[4][8];
#pragma unroll
    for (int i = 0; i < 4; ++i)
#pragma unroll
        for (int j = 0; j < 8; ++j) acc[i][j] = 0.f;

    for (int kp = 0; kp < 4; ++kp) {
        // W panel: 32x128 floats
        {
            const float4* Wp = (const float4*)(W + (size_t)kp * 32 * 128);
            float4* Wd = (float4*)(&Ws[0][0]);
#pragma unroll
            for (int i = 0; i < 4; ++i) Wd[t + i * 256] = Wp[t + i * 256];
        }
        // X panel transposed: 64 rows x 32 k
        {
#pragma unroll
            for (int i = 0; i < 8; ++i) {
                int idx = t + i * 256;      // 0..2047
                int rr = idx >> 5;          // 0..63
                int kk = idx & 31;
                int grow = row0 + rr;
                float v = 0.f;
                if (grow < nrows) v = X[(size_t)grow * 128 + kp * 32 + kk];
                XsT[kk][rr] = v;
            }
        }
        __syncthreads();
#pragma unroll 8
        for (int kk = 0; kk < 32; ++kk) {
            float4 xv = *(const float4*)(&XsT[kk][r4]);
            float4 wa = *(const float4*)(&Ws[kk][c8]);
            float4 wb = *(const float4*)(&Ws[kk][c8 + 4]);
            float xs[4] = {xv.x, xv.y, xv.z, xv.w};
            float wv[8] = {wa.x, wa.y, wa.z, wa.w, wb.x, wb.y, wb.z, wb.w};
#pragma unroll
            for (int i = 0; i < 4; ++i)
#pragma unroll
                for (int j = 0; j < 8; ++j) acc[i][j] += xs[i] * wv[j];
        }
        __syncthreads();
    }
#pragma unroll
    for (int i = 0; i < 4; ++i) {
        int grow = row0 + r4 + i;
        if (grow < nrows) {
            float4* Yp = (float4*)(Y + (size_t)grow * 128 + c8);
            Yp[0] = make_float4(acc[i][0], acc[i][1], acc[i][2], acc[i][3]);
            Yp[1] = make_float4(acc[i][4], acc[i][5], acc[i][6], acc[i][7]);
        }
    }
}

// ---------------- edge scatter: out[dst] += t[src] * dinv[src]*dinv[dst] ----------------
// 8 edges per 256-thread block; 32 lanes x float4 per edge row.
__global__ __launch_bounds__(256) void scatter_k(const float* __restrict__ T,
                                                 const int* __restrict__ src,
                                                 const int* __restrict__ dst,
                                                 const float* __restrict__ dinv,
                                                 float* __restrict__ out) {
    int e = blockIdx.x * 8 + (threadIdx.x >> 5);
    if (e >= N_EDGES) return;
    int j4 = (threadIdx.x & 31) * 4;
    int s = src[e], d = dst[e];
    float coef = dinv[s] * dinv[d];
    const float4 v = *(const float4*)(T + (size_t)s * HD + j4);
    float* o = out + (size_t)d * HD + j4;
    atomicAdd(o + 0, v.x * coef);
    atomicAdd(o + 1, v.y * coef);
    atomicAdd(o + 2, v.z * coef);
    atomicAdd(o + 3, v.w * coef);
}

// ---------------- finalize: out += t*dinv^2 + b, optional relu ----------------
__global__ __launch_bounds__(256) void finalize_k(float* __restrict__ out,
                                                  const float* __restrict__ T,
                                                  const float* __restrict__ dinv,
                                                  const float* __restrict__ b,
                                                  int relu) {
    size_t idx = (size_t)blockIdx.x * 256 + threadIdx.x;   // float4 index
    size_t n4 = (size_t)N_NODES * HD / 4;
    if (idx >= n4) return;
    int i = (int)(idx >> 5);
    int j4 = (int)((idx & 31) * 4);
    float di = dinv[i];
    float sc = di * di;
    float4 t4 = *(const float4*)(T + idx * 4);
    float4 o4 = *(const float4*)(out + idx * 4);
    float4 b4 = *(const float4*)(b + j4);
    float4 r;
    r.x = o4.x + t4.x * sc + b4.x;
    r.y = o4.y + t4.y * sc + b4.y;
    r.z = o4.z + t4.z * sc + b4.z;
    r.w = o4.w + t4.w * sc + b4.w;
    if (relu) {
        r.x = fmaxf(r.x, 0.f);
        r.y = fmaxf(r.y, 0.f);
        r.z = fmaxf(r.z, 0.f);
        r.w = fmaxf(r.w, 0.f);
    }
    *(float4*)(out + idx * 4) = r;
}

// ---------------- global mean pool (sums + counts via atomics) ----------------
__global__ __launch_bounds__(256) void pool_k(const float* __restrict__ H2,
                                              const int* __restrict__ batch,
                                              float* __restrict__ sums,
                                              float* __restrict__ cnt) {
    int i = blockIdx.x * 8 + (threadIdx.x >> 5);
    if (i >= N_NODES) return;
    int j4 = (threadIdx.x & 31) * 4;
    int g = batch[i];
    const float4 v = *(const float4*)(H2 + (size_t)i * HD + j4);
    float* s = sums + (size_t)g * HD + j4;
    atomicAdd(s + 0, v.x);
    atomicAdd(s + 1, v.y);
    atomicAdd(s + 2, v.z);
    atomicAdd(s + 3, v.w);
    if (j4 == 0) atomicAdd(cnt + g, 1.0f);
}

// ---------------- head: out[g,o] = (sums[g,:]/max(cnt,1)) @ Wh + bh ----------------
__global__ __launch_bounds__(512) void head_k(const float* __restrict__ sums,
                                              const float* __restrict__ cnt,
                                              const float* __restrict__ Wh,
                                              const float* __restrict__ bh,
                                              float* __restrict__ out) {
    int t = threadIdx.x;               // 512 = 64 graphs * 8 outs
    int g = t >> 3, o = t & 7;
    float inv = 1.0f / fmaxf(cnt[g], 1.0f);
    float acc = bh[o];
    for (int h = 0; h < HD; ++h)
        acc += sums[g * HD + h] * inv * Wh[h * NOUT + o];
    out[g * NOUT + o] = acc;
}

extern "C" void kernel_launch(void* const* d_in, const int* in_sizes, int n_in,
                              void* d_out, int out_size, void* d_ws, size_t ws_size,
                              hipStream_t stream) {
    const float* x  = (const float*)d_in[0];
    const int*   ei = (const int*)d_in[1];
    const int*   batch = (const int*)d_in[2];
    const float* W0 = (const float*)d_in[3];
    const float* b0 = (const float*)d_in[4];
    const float* W1 = (const float*)d_in[5];
    const float* b1 = (const float*)d_in[6];
    const float* W2 = (const float*)d_in[7];
    const float* b2 = (const float*)d_in[8];
    const float* Wh = (const float*)d_in[9];
    const float* bh = (const float*)d_in[10];
    float* out = (float*)d_out;

    const int* src = ei;
    const int* dst = ei + N_EDGES;

    float* ws   = (float*)d_ws;
    float* dinv = ws;                                    // N (holds deg first)
    float* A    = ws + 51200;                            // N*HD
    float* B    = A + (size_t)N_NODES * HD;              // N*HD
    float* C    = B + (size_t)N_NODES * HD;              // N*HD
    float* sums = C + (size_t)N_NODES * HD;              // G*HD
    float* cnt  = sums + NGRAPH * HD;                    // G

    const size_t hbytes = (size_t)N_NODES * HD * sizeof(float);
    const int mmGrid = (N_NODES + 63) / 64;
    const int scGrid = N_EDGES / 8;
    const int fiGrid = (N_NODES * HD / 4 + 255) / 256;

    // degree -> dinv
    hipMemsetAsync(dinv, 0, N_NODES * sizeof(float), stream);
    deg_k<<<(N_EDGES + 255) / 256, 256, 0, stream>>>(dst, dinv);
    dinv_k<<<(N_NODES + 255) / 256, 256, 0, stream>>>(dinv);

    // layer 0: x -> B (relu)
    matmul_k<<<mmGrid, 256, 0, stream>>>(x, W0, A, N_NODES);
    hipMemsetAsync(B, 0, hbytes, stream);
    scatter_k<<<scGrid, 256, 0, stream>>>(A, src, dst, dinv, B);
    finalize_k<<<fiGrid, 256, 0, stream>>>(B, A, dinv, b0, 1);

    // layer 1: B -> C (relu)
    matmul_k<<<mmGrid, 256, 0, stream>>>(B, W1, A, N_NODES);
    hipMemsetAsync(C, 0, hbytes, stream);
    scatter_k<<<scGrid, 256, 0, stream>>>(A, src, dst, dinv, C);
    finalize_k<<<fiGrid, 256, 0, stream>>>(C, A, dinv, b1, 1);

    // layer 2: C -> B (no relu)
    matmul_k<<<mmGrid, 256, 0, stream>>>(C, W2, A, N_NODES);
    hipMemsetAsync(B, 0, hbytes, stream);
    scatter_k<<<scGrid, 256, 0, stream>>>(A, src, dst, dinv, B);
    finalize_k<<<fiGrid, 256, 0, stream>>>(B, A, dinv, b2, 0);

    // pool + head
    hipMemsetAsync(sums, 0, (NGRAPH * HD + NGRAPH) * sizeof(float), stream);
    pool_k<<<(N_NODES + 7) / 8, 256, 0, stream>>>(B, batch, sums, cnt);
    head_k<<<1, 512, 0, stream>>>(sums, cnt, Wh, bh, out);
}

// Round 2
// 1025.081 us; speedup vs baseline: 4.6279x; 4.6279x over previous
//
#include <hip/hip_runtime.h>

#define N_NODES 50000
#define N_EDGES 800000
#define HD 128
#define NGRAPH 64
#define NOUT 8

// ---------------- degree (int) ----------------
__global__ __launch_bounds__(256) void deg_k(const int* __restrict__ dst, int* __restrict__ deg) {
    int e = blockIdx.x * 256 + threadIdx.x;
    if (e < N_EDGES) atomicAdd(&deg[dst[e]], 1);
}

__global__ __launch_bounds__(256) void dinv_k(const int* __restrict__ deg, float* __restrict__ dinv) {
    int i = blockIdx.x * 256 + threadIdx.x;
    if (i < N_NODES) dinv[i] = 1.0f / sqrtf((float)deg[i] + 1.0f);
}

// ---------------- exclusive scan over deg -> rowptr (single block) ----------------
__global__ __launch_bounds__(1024) void scan_k(const int* __restrict__ deg,
                                               int* __restrict__ rowptr,
                                               int* __restrict__ cursor) {
    __shared__ int ssum[1024];
    const int t = threadIdx.x;
    const int CH = (N_NODES + 1023) / 1024;     // 49
    int beg = t * CH;
    int end = beg + CH; if (end > N_NODES) end = N_NODES;
    if (beg > N_NODES) beg = N_NODES;
    int s = 0;
    for (int i = beg; i < end; ++i) s += deg[i];
    ssum[t] = s;
    // Hillis-Steele inclusive scan
    for (int off = 1; off < 1024; off <<= 1) {
        __syncthreads();
        int v = (t >= off) ? ssum[t - off] : 0;
        __syncthreads();
        ssum[t] += v;
    }
    __syncthreads();
    int prefix = (t == 0) ? 0 : ssum[t - 1];
    for (int i = beg; i < end; ++i) {
        rowptr[i] = prefix; cursor[i] = prefix;
        prefix += deg[i];
    }
    if (t == 0) rowptr[N_NODES] = ssum[1023];
}

// ---------------- fill CSR: bucket edges by dst, precompute coef ----------------
__global__ __launch_bounds__(256) void fill_k(const int* __restrict__ src,
                                              const int* __restrict__ dst,
                                              const float* __restrict__ dinv,
                                              int* __restrict__ cursor,
                                              int* __restrict__ csr_src,
                                              float* __restrict__ csr_coef) {
    int e = blockIdx.x * 256 + threadIdx.x;
    if (e >= N_EDGES) return;
    int s = src[e], d = dst[e];
    int pos = atomicAdd(&cursor[d], 1);
    csr_src[pos] = s;
    csr_coef[pos] = dinv[s] * dinv[d];
}

// ---------------- matmul: Y[nrows,128] = X[nrows,128] @ W[128,128] ----------------
__global__ __launch_bounds__(256) void matmul_k(const float* __restrict__ X,
                                                const float* __restrict__ W,
                                                float* __restrict__ Y,
                                                int nrows) {
    __shared__ float XsT[32][68];
    __shared__ float Ws[32][128];
    const int t = threadIdx.x;
    const int c8 = (t & 15) * 8;
    const int r4 = (t >> 4) * 4;
    const int row0 = blockIdx.x * 64;

    float acc[4][8];
#pragma unroll
    for (int i = 0; i < 4; ++i)
#pragma unroll
        for (int j = 0; j < 8; ++j) acc[i][j] = 0.f;

    for (int kp = 0; kp < 4; ++kp) {
        {
            const float4* Wp = (const float4*)(W + (size_t)kp * 32 * 128);
            float4* Wd = (float4*)(&Ws[0][0]);
#pragma unroll
            for (int i = 0; i < 4; ++i) Wd[t + i * 256] = Wp[t + i * 256];
        }
        {
#pragma unroll
            for (int i = 0; i < 8; ++i) {
                int idx = t + i * 256;
                int rr = idx >> 5;
                int kk = idx & 31;
                int grow = row0 + rr;
                float v = 0.f;
                if (grow < nrows) v = X[(size_t)grow * 128 + kp * 32 + kk];
                XsT[kk][rr] = v;
            }
        }
        __syncthreads();
#pragma unroll 8
        for (int kk = 0; kk < 32; ++kk) {
            float4 xv = *(const float4*)(&XsT[kk][r4]);
            float4 wa = *(const float4*)(&Ws[kk][c8]);
            float4 wb = *(const float4*)(&Ws[kk][c8 + 4]);
            float xs[4] = {xv.x, xv.y, xv.z, xv.w};
            float wv[8] = {wa.x, wa.y, wa.z, wa.w, wb.x, wb.y, wb.z, wb.w};
#pragma unroll
            for (int i = 0; i < 4; ++i)
#pragma unroll
                for (int j = 0; j < 8; ++j) acc[i][j] += xs[i] * wv[j];
        }
        __syncthreads();
    }
#pragma unroll
    for (int i = 0; i < 4; ++i) {
        int grow = row0 + r4 + i;
        if (grow < nrows) {
            float4* Yp = (float4*)(Y + (size_t)grow * 128 + c8);
            Yp[0] = make_float4(acc[i][0], acc[i][1], acc[i][2], acc[i][3]);
            Yp[1] = make_float4(acc[i][4], acc[i][5], acc[i][6], acc[i][7]);
        }
    }
}

// ---------------- gather: out[i] = sum_{e in CSR[i]} T[src_e]*coef_e + T[i]*dinv[i]^2 + b ----------------
// 32-lane group per node, 8 nodes per 256-thread block. Fuses self-loop+bias+relu.
__global__ __launch_bounds__(256) void gather_k(const float* __restrict__ T,
                                                const int* __restrict__ rowptr,
                                                const int* __restrict__ csr_src,
                                                const float* __restrict__ csr_coef,
                                                const float* __restrict__ dinv,
                                                const float* __restrict__ b,
                                                float* __restrict__ out,
                                                int relu) {
    int i = blockIdx.x * 8 + (threadIdx.x >> 5);
    if (i >= N_NODES) return;
    const int j4 = (threadIdx.x & 31) * 4;
    const int beg = rowptr[i], end = rowptr[i + 1];

    float4 acc = make_float4(0.f, 0.f, 0.f, 0.f);
    int e = beg;
    // 4-way unroll: independent loads in flight
    for (; e + 3 < end; e += 4) {
        int s0 = csr_src[e], s1 = csr_src[e + 1], s2 = csr_src[e + 2], s3 = csr_src[e + 3];
        float c0 = csr_coef[e], c1 = csr_coef[e + 1], c2 = csr_coef[e + 2], c3 = csr_coef[e + 3];
        float4 v0 = *(const float4*)(T + (size_t)s0 * HD + j4);
        float4 v1 = *(const float4*)(T + (size_t)s1 * HD + j4);
        float4 v2 = *(const float4*)(T + (size_t)s2 * HD + j4);
        float4 v3 = *(const float4*)(T + (size_t)s3 * HD + j4);
        acc.x += v0.x * c0 + v1.x * c1 + v2.x * c2 + v3.x * c3;
        acc.y += v0.y * c0 + v1.y * c1 + v2.y * c2 + v3.y * c3;
        acc.z += v0.z * c0 + v1.z * c1 + v2.z * c2 + v3.z * c3;
        acc.w += v0.w * c0 + v1.w * c1 + v2.w * c2 + v3.w * c3;
    }
    for (; e < end; ++e) {
        int s = csr_src[e];
        float c = csr_coef[e];
        float4 v = *(const float4*)(T + (size_t)s * HD + j4);
        acc.x += v.x * c; acc.y += v.y * c; acc.z += v.z * c; acc.w += v.w * c;
    }
    // self-loop + bias
    float di = dinv[i];
    float sc = di * di;
    float4 tv = *(const float4*)(T + (size_t)i * HD + j4);
    float4 bv = *(const float4*)(b + j4);
    acc.x += tv.x * sc + bv.x;
    acc.y += tv.y * sc + bv.y;
    acc.z += tv.z * sc + bv.z;
    acc.w += tv.w * sc + bv.w;
    if (relu) {
        acc.x = fmaxf(acc.x, 0.f); acc.y = fmaxf(acc.y, 0.f);
        acc.z = fmaxf(acc.z, 0.f); acc.w = fmaxf(acc.w, 0.f);
    }
    *(float4*)(out + (size_t)i * HD + j4) = acc;
}

// ---------------- global mean pool ----------------
__global__ __launch_bounds__(256) void pool_k(const float* __restrict__ H2,
                                              const int* __restrict__ batch,
                                              float* __restrict__ sums,
                                              float* __restrict__ cnt) {
    int i = blockIdx.x * 8 + (threadIdx.x >> 5);
    if (i >= N_NODES) return;
    int j4 = (threadIdx.x & 31) * 4;
    int g = batch[i];
    const float4 v = *(const float4*)(H2 + (size_t)i * HD + j4);
    float* s = sums + (size_t)g * HD + j4;
    atomicAdd(s + 0, v.x);
    atomicAdd(s + 1, v.y);
    atomicAdd(s + 2, v.z);
    atomicAdd(s + 3, v.w);
    if (j4 == 0) atomicAdd(cnt + g, 1.0f);
}

// ---------------- head ----------------
__global__ __launch_bounds__(512) void head_k(const float* __restrict__ sums,
                                              const float* __restrict__ cnt,
                                              const float* __restrict__ Wh,
                                              const float* __restrict__ bh,
                                              float* __restrict__ out) {
    int t = threadIdx.x;
    int g = t >> 3, o = t & 7;
    float inv = 1.0f / fmaxf(cnt[g], 1.0f);
    float acc = bh[o];
    for (int h = 0; h < HD; ++h)
        acc += sums[g * HD + h] * inv * Wh[h * NOUT + o];
    out[g * NOUT + o] = acc;
}

extern "C" void kernel_launch(void* const* d_in, const int* in_sizes, int n_in,
                              void* d_out, int out_size, void* d_ws, size_t ws_size,
                              hipStream_t stream) {
    const float* x  = (const float*)d_in[0];
    const int*   ei = (const int*)d_in[1];
    const int*   batch = (const int*)d_in[2];
    const float* W0 = (const float*)d_in[3];
    const float* b0 = (const float*)d_in[4];
    const float* W1 = (const float*)d_in[5];
    const float* b1 = (const float*)d_in[6];
    const float* W2 = (const float*)d_in[7];
    const float* b2 = (const float*)d_in[8];
    const float* Wh = (const float*)d_in[9];
    const float* bh = (const float*)d_in[10];
    float* out = (float*)d_out;

    const int* src = ei;
    const int* dst = ei + N_EDGES;

    // workspace layout (4-byte element offsets; all float4 bases 16B-aligned)
    char* wsb = (char*)d_ws;
    int*   deg      = (int*)(wsb + 0);                          // N
    float* dinv     = (float*)(wsb + 200000);                   // N
    int*   rowptr   = (int*)(wsb + 400000);                     // N+1
    int*   cursor   = (int*)(wsb + 600016);                     // N
    int*   csr_src  = (int*)(wsb + 800016);                     // E
    float* csr_coef = (float*)(wsb + 4000016);                  // E
    float* A        = (float*)(wsb + 7200016);                  // N*HD
    float* B        = (float*)(wsb + 32800016);                 // N*HD
    float* sums     = (float*)(wsb + 58400016);                 // G*HD
    float* cnt      = (float*)(wsb + 58432784);                 // G

    const int mmGrid = (N_NODES + 63) / 64;
    const int gaGrid = (N_NODES + 7) / 8;

    // ---- CSR build (per-call; ws is re-poisoned before every timed launch) ----
    hipMemsetAsync(deg, 0, N_NODES * sizeof(int), stream);
    deg_k<<<(N_EDGES + 255) / 256, 256, 0, stream>>>(dst, deg);
    dinv_k<<<(N_NODES + 255) / 256, 256, 0, stream>>>(deg, dinv);
    scan_k<<<1, 1024, 0, stream>>>(deg, rowptr, cursor);
    fill_k<<<(N_EDGES + 255) / 256, 256, 0, stream>>>(src, dst, dinv, cursor, csr_src, csr_coef);

    // ---- layer 0: x -> (matmul) A -> (gather+relu) B ----
    matmul_k<<<mmGrid, 256, 0, stream>>>(x, W0, A, N_NODES);
    gather_k<<<gaGrid, 256, 0, stream>>>(A, rowptr, csr_src, csr_coef, dinv, b0, B, 1);

    // ---- layer 1: B -> A -> B ----
    matmul_k<<<mmGrid, 256, 0, stream>>>(B, W1, A, N_NODES);
    gather_k<<<gaGrid, 256, 0, stream>>>(A, rowptr, csr_src, csr_coef, dinv, b1, B, 1);

    // ---- layer 2: B -> A -> B (no relu) ----
    matmul_k<<<mmGrid, 256, 0, stream>>>(B, W2, A, N_NODES);
    gather_k<<<gaGrid, 256, 0, stream>>>(A, rowptr, csr_src, csr_coef, dinv, b2, B, 0);

    // ---- pool + head ----
    hipMemsetAsync(sums, 0, (NGRAPH * HD + NGRAPH) * sizeof(float), stream);
    pool_k<<<gaGrid, 256, 0, stream>>>(B, batch, sums, cnt);
    head_k<<<1, 512, 0, stream>>>(sums, cnt, Wh, bh, out);
}

// Round 3
// 630.004 us; speedup vs baseline: 7.5301x; 1.6271x over previous
//
#include <hip/hip_runtime.h>

#define N_NODES 50000
#define N_EDGES 800000
#define HD 128
#define NGRAPH 64
#define NOUT 8

// ---------------- degree (int) ----------------
__global__ __launch_bounds__(256) void deg_k(const int* __restrict__ dst, int* __restrict__ deg) {
    int e = blockIdx.x * 256 + threadIdx.x;
    if (e < N_EDGES) atomicAdd(&deg[dst[e]], 1);
}

__global__ __launch_bounds__(256) void dinv_k(const int* __restrict__ deg, float* __restrict__ dinv) {
    int i = blockIdx.x * 256 + threadIdx.x;
    if (i < N_NODES) dinv[i] = 1.0f / sqrtf((float)deg[i] + 1.0f);
}

// ---------------- exclusive scan over deg -> rowptr (single block) ----------------
__global__ __launch_bounds__(1024) void scan_k(const int* __restrict__ deg,
                                               int* __restrict__ rowptr,
                                               int* __restrict__ cursor) {
    __shared__ int ssum[1024];
    const int t = threadIdx.x;
    const int CH = (N_NODES + 1023) / 1024;     // 49
    int beg = t * CH;
    int end = beg + CH; if (end > N_NODES) end = N_NODES;
    if (beg > N_NODES) beg = N_NODES;
    int s = 0;
    for (int i = beg; i < end; ++i) s += deg[i];
    ssum[t] = s;
    for (int off = 1; off < 1024; off <<= 1) {
        __syncthreads();
        int v = (t >= off) ? ssum[t - off] : 0;
        __syncthreads();
        ssum[t] += v;
    }
    __syncthreads();
    int prefix = (t == 0) ? 0 : ssum[t - 1];
    for (int i = beg; i < end; ++i) {
        rowptr[i] = prefix; cursor[i] = prefix;
        prefix += deg[i];
    }
    if (t == 0) rowptr[N_NODES] = ssum[1023];
}

// ---------------- fill CSR: bucket edges by dst, precompute coef ----------------
__global__ __launch_bounds__(256) void fill_k(const int* __restrict__ src,
                                              const int* __restrict__ dst,
                                              const float* __restrict__ dinv,
                                              int* __restrict__ cursor,
                                              int* __restrict__ csr_src,
                                              float* __restrict__ csr_coef) {
    int e = blockIdx.x * 256 + threadIdx.x;
    if (e >= N_EDGES) return;
    int s = src[e], d = dst[e];
    int pos = atomicAdd(&cursor[d], 1);
    csr_src[pos] = s;
    csr_coef[pos] = dinv[s] * dinv[d];
}

// ---------------- matmul: Y[nrows,128] = X[nrows,128] @ W[128,128] ----------------
__global__ __launch_bounds__(256) void matmul_k(const float* __restrict__ X,
                                                const float* __restrict__ W,
                                                float* __restrict__ Y,
                                                int nrows) {
    __shared__ float XsT[32][68];
    __shared__ float Ws[32][128];
    const int t = threadIdx.x;
    const int c8 = (t & 15) * 8;
    const int r4 = (t >> 4) * 4;
    const int row0 = blockIdx.x * 64;

    float acc[4][8];
#pragma unroll
    for (int i = 0; i < 4; ++i)
#pragma unroll
        for (int j = 0; j < 8; ++j) acc[i][j] = 0.f;

    for (int kp = 0; kp < 4; ++kp) {
        {
            const float4* Wp = (const float4*)(W + (size_t)kp * 32 * 128);
            float4* Wd = (float4*)(&Ws[0][0]);
#pragma unroll
            for (int i = 0; i < 4; ++i) Wd[t + i * 256] = Wp[t + i * 256];
        }
        {
#pragma unroll
            for (int i = 0; i < 8; ++i) {
                int idx = t + i * 256;
                int rr = idx >> 5;
                int kk = idx & 31;
                int grow = row0 + rr;
                float v = 0.f;
                if (grow < nrows) v = X[(size_t)grow * 128 + kp * 32 + kk];
                XsT[kk][rr] = v;
            }
        }
        __syncthreads();
#pragma unroll 8
        for (int kk = 0; kk < 32; ++kk) {
            float4 xv = *(const float4*)(&XsT[kk][r4]);
            float4 wa = *(const float4*)(&Ws[kk][c8]);
            float4 wb = *(const float4*)(&Ws[kk][c8 + 4]);
            float xs[4] = {xv.x, xv.y, xv.z, xv.w};
            float wv[8] = {wa.x, wa.y, wa.z, wa.w, wb.x, wb.y, wb.z, wb.w};
#pragma unroll
            for (int i = 0; i < 4; ++i)
#pragma unroll
                for (int j = 0; j < 8; ++j) acc[i][j] += xs[i] * wv[j];
        }
        __syncthreads();
    }
#pragma unroll
    for (int i = 0; i < 4; ++i) {
        int grow = row0 + r4 + i;
        if (grow < nrows) {
            float4* Yp = (float4*)(Y + (size_t)grow * 128 + c8);
            Yp[0] = make_float4(acc[i][0], acc[i][1], acc[i][2], acc[i][3]);
            Yp[1] = make_float4(acc[i][4], acc[i][5], acc[i][6], acc[i][7]);
        }
    }
}

// ---------------- gather: out[i] = sum_{e in CSR[i]} T[src_e]*coef_e + T[i]*dinv[i]^2 + b ----------------
__global__ __launch_bounds__(256) void gather_k(const float* __restrict__ T,
                                                const int* __restrict__ rowptr,
                                                const int* __restrict__ csr_src,
                                                const float* __restrict__ csr_coef,
                                                const float* __restrict__ dinv,
                                                const float* __restrict__ b,
                                                float* __restrict__ out,
                                                int relu) {
    int i = blockIdx.x * 8 + (threadIdx.x >> 5);
    if (i >= N_NODES) return;
    const int j4 = (threadIdx.x & 31) * 4;
    const int beg = rowptr[i], end = rowptr[i + 1];

    float4 acc = make_float4(0.f, 0.f, 0.f, 0.f);
    int e = beg;
    for (; e + 3 < end; e += 4) {
        int s0 = csr_src[e], s1 = csr_src[e + 1], s2 = csr_src[e + 2], s3 = csr_src[e + 3];
        float c0 = csr_coef[e], c1 = csr_coef[e + 1], c2 = csr_coef[e + 2], c3 = csr_coef[e + 3];
        float4 v0 = *(const float4*)(T + (size_t)s0 * HD + j4);
        float4 v1 = *(const float4*)(T + (size_t)s1 * HD + j4);
        float4 v2 = *(const float4*)(T + (size_t)s2 * HD + j4);
        float4 v3 = *(const float4*)(T + (size_t)s3 * HD + j4);
        acc.x += v0.x * c0 + v1.x * c1 + v2.x * c2 + v3.x * c3;
        acc.y += v0.y * c0 + v1.y * c1 + v2.y * c2 + v3.y * c3;
        acc.z += v0.z * c0 + v1.z * c1 + v2.z * c2 + v3.z * c3;
        acc.w += v0.w * c0 + v1.w * c1 + v2.w * c2 + v3.w * c3;
    }
    for (; e < end; ++e) {
        int s = csr_src[e];
        float c = csr_coef[e];
        float4 v = *(const float4*)(T + (size_t)s * HD + j4);
        acc.x += v.x * c; acc.y += v.y * c; acc.z += v.z * c; acc.w += v.w * c;
    }
    float di = dinv[i];
    float sc = di * di;
    float4 tv = *(const float4*)(T + (size_t)i * HD + j4);
    float4 bv = *(const float4*)(b + j4);
    acc.x += tv.x * sc + bv.x;
    acc.y += tv.y * sc + bv.y;
    acc.z += tv.z * sc + bv.z;
    acc.w += tv.w * sc + bv.w;
    if (relu) {
        acc.x = fmaxf(acc.x, 0.f); acc.y = fmaxf(acc.y, 0.f);
        acc.z = fmaxf(acc.z, 0.f); acc.w = fmaxf(acc.w, 0.f);
    }
    *(float4*)(out + (size_t)i * HD + j4) = acc;
}

// ---------------- global mean pool: run-length segmented reduction over sorted batch ----------------
// Block = 256 threads = 2 halves x 128 features. Each half walks 64 consecutive nodes,
// accumulating per-feature in a register while batch[i] is constant; one atomic per run.
__global__ __launch_bounds__(256) void pool2_k(const float* __restrict__ H2,
                                               const int* __restrict__ batch,
                                               float* __restrict__ sums,
                                               float* __restrict__ cnt) {
    const int t = threadIdx.x;
    const int f = t & 127;
    const int half = t >> 7;
    int i0 = blockIdx.x * 128 + half * 64;
    if (i0 >= N_NODES) return;
    int i1 = i0 + 64; if (i1 > N_NODES) i1 = N_NODES;

    int cur = batch[i0];
    float acc = 0.f;
    float c = 0.f;
    for (int i = i0; i < i1; ++i) {
        int g = batch[i];
        if (g != cur) {               // uniform across the 128-thread half
            atomicAdd(&sums[cur * HD + f], acc);
            if (f == 0) atomicAdd(&cnt[cur], c);
            acc = 0.f; c = 0.f; cur = g;
        }
        acc += H2[(size_t)i * HD + f];
        c += 1.f;
    }
    atomicAdd(&sums[cur * HD + f], acc);
    if (f == 0) atomicAdd(&cnt[cur], c);
}

// ---------------- head ----------------
__global__ __launch_bounds__(512) void head_k(const float* __restrict__ sums,
                                              const float* __restrict__ cnt,
                                              const float* __restrict__ Wh,
                                              const float* __restrict__ bh,
                                              float* __restrict__ out) {
    int t = threadIdx.x;
    int g = t >> 3, o = t & 7;
    float inv = 1.0f / fmaxf(cnt[g], 1.0f);
    float acc = bh[o];
    for (int h = 0; h < HD; ++h)
        acc += sums[g * HD + h] * inv * Wh[h * NOUT + o];
    out[g * NOUT + o] = acc;
}

extern "C" void kernel_launch(void* const* d_in, const int* in_sizes, int n_in,
                              void* d_out, int out_size, void* d_ws, size_t ws_size,
                              hipStream_t stream) {
    const float* x  = (const float*)d_in[0];
    const int*   ei = (const int*)d_in[1];
    const int*   batch = (const int*)d_in[2];
    const float* W0 = (const float*)d_in[3];
    const float* b0 = (const float*)d_in[4];
    const float* W1 = (const float*)d_in[5];
    const float* b1 = (const float*)d_in[6];
    const float* W2 = (const float*)d_in[7];
    const float* b2 = (const float*)d_in[8];
    const float* Wh = (const float*)d_in[9];
    const float* bh = (const float*)d_in[10];
    float* out = (float*)d_out;

    const int* src = ei;
    const int* dst = ei + N_EDGES;

    char* wsb = (char*)d_ws;
    int*   deg      = (int*)(wsb + 0);                          // N
    float* dinv     = (float*)(wsb + 200000);                   // N
    int*   rowptr   = (int*)(wsb + 400000);                     // N+1
    int*   cursor   = (int*)(wsb + 600016);                     // N
    int*   csr_src  = (int*)(wsb + 800016);                     // E
    float* csr_coef = (float*)(wsb + 4000016);                  // E
    float* A        = (float*)(wsb + 7200016);                  // N*HD
    float* B        = (float*)(wsb + 32800016);                 // N*HD
    float* sums     = (float*)(wsb + 58400016);                 // G*HD
    float* cnt      = (float*)(wsb + 58432784);                 // G

    const int mmGrid = (N_NODES + 63) / 64;
    const int gaGrid = (N_NODES + 7) / 8;

    // ---- CSR build ----
    hipMemsetAsync(deg, 0, N_NODES * sizeof(int), stream);
    deg_k<<<(N_EDGES + 255) / 256, 256, 0, stream>>>(dst, deg);
    dinv_k<<<(N_NODES + 255) / 256, 256, 0, stream>>>(deg, dinv);
    scan_k<<<1, 1024, 0, stream>>>(deg, rowptr, cursor);
    fill_k<<<(N_EDGES + 255) / 256, 256, 0, stream>>>(src, dst, dinv, cursor, csr_src, csr_coef);

    // ---- layer 0 ----
    matmul_k<<<mmGrid, 256, 0, stream>>>(x, W0, A, N_NODES);
    gather_k<<<gaGrid, 256, 0, stream>>>(A, rowptr, csr_src, csr_coef, dinv, b0, B, 1);

    // ---- layer 1 ----
    matmul_k<<<mmGrid, 256, 0, stream>>>(B, W1, A, N_NODES);
    gather_k<<<gaGrid, 256, 0, stream>>>(A, rowptr, csr_src, csr_coef, dinv, b1, B, 1);

    // ---- layer 2 (no relu) ----
    matmul_k<<<mmGrid, 256, 0, stream>>>(B, W2, A, N_NODES);
    gather_k<<<gaGrid, 256, 0, stream>>>(A, rowptr, csr_src, csr_coef, dinv, b2, B, 0);

    // ---- pool + head ----
    hipMemsetAsync(sums, 0, (NGRAPH * HD + NGRAPH) * sizeof(float), stream);
    pool2_k<<<(N_NODES + 127) / 128, 256, 0, stream>>>(B, batch, sums, cnt);
    head_k<<<1, 512, 0, stream>>>(sums, cnt, Wh, bh, out);
}

// Round 4
// 530.828 us; speedup vs baseline: 8.9370x; 1.1868x over previous
//
#include <hip/hip_runtime.h>

#define N_NODES 50000
#define N_EDGES 800000
#define HD 128
#define NGRAPH 64
#define NOUT 8

#define SCAN_CHUNK 512
#define SCAN_BLOCKS ((N_NODES + SCAN_CHUNK - 1) / SCAN_CHUNK)   // 98

// ---------------- degree (int) ----------------
__global__ __launch_bounds__(256) void deg_k(const int* __restrict__ dst, int* __restrict__ deg) {
    int e = blockIdx.x * 256 + threadIdx.x;
    if (e < N_EDGES) atomicAdd(&deg[dst[e]], 1);
}

__global__ __launch_bounds__(256) void dinv_k(const int* __restrict__ deg, float* __restrict__ dinv) {
    int i = blockIdx.x * 256 + threadIdx.x;
    if (i < N_NODES) dinv[i] = 1.0f / sqrtf((float)deg[i] + 1.0f);
}

// ---------------- two-level scan: per-chunk partials ----------------
__global__ __launch_bounds__(256) void part_k(const int* __restrict__ deg, int* __restrict__ part) {
    __shared__ int red[256];
    const int t = threadIdx.x;
    int i0 = blockIdx.x * SCAN_CHUNK + 2 * t;
    int s = 0;
    if (i0 < N_NODES) s += deg[i0];
    if (i0 + 1 < N_NODES) s += deg[i0 + 1];
    red[t] = s;
    __syncthreads();
    for (int off = 128; off > 0; off >>= 1) {
        if (t < off) red[t] += red[t + off];
        __syncthreads();
    }
    if (t == 0) part[blockIdx.x] = red[0];
}

// ---------------- scan the 98 partials (exclusive) ----------------
__global__ __launch_bounds__(128) void scanpart_k(const int* __restrict__ part,
                                                  int* __restrict__ partoff,
                                                  int* __restrict__ rowptr) {
    __shared__ int sh[128];
    const int t = threadIdx.x;
    int v = (t < SCAN_BLOCKS) ? part[t] : 0;
    sh[t] = v;
    for (int off = 1; off < 128; off <<= 1) {
        __syncthreads();
        int u = (t >= off) ? sh[t - off] : 0;
        __syncthreads();
        sh[t] += u;
    }
    __syncthreads();
    if (t < SCAN_BLOCKS) partoff[t] = sh[t] - v;   // exclusive
    if (t == 0) rowptr[N_NODES] = N_EDGES;
}

// ---------------- block-local scan + rowptr/cursor fill ----------------
__global__ __launch_bounds__(256) void rowfill_k(const int* __restrict__ deg,
                                                 const int* __restrict__ partoff,
                                                 int* __restrict__ rowptr,
                                                 int* __restrict__ cursor) {
    __shared__ int sh[256];
    const int t = threadIdx.x;
    int i0 = blockIdx.x * SCAN_CHUNK + 2 * t;
    int d0 = (i0 < N_NODES) ? deg[i0] : 0;
    int d1 = (i0 + 1 < N_NODES) ? deg[i0 + 1] : 0;
    int s = d0 + d1;
    sh[t] = s;
    for (int off = 1; off < 256; off <<= 1) {
        __syncthreads();
        int u = (t >= off) ? sh[t - off] : 0;
        __syncthreads();
        sh[t] += u;
    }
    __syncthreads();
    int p = partoff[blockIdx.x] + sh[t] - s;       // exclusive prefix at i0
    if (i0 < N_NODES)     { rowptr[i0] = p;          cursor[i0] = p; }
    if (i0 + 1 < N_NODES) { rowptr[i0 + 1] = p + d0; cursor[i0 + 1] = p + d0; }
}

// ---------------- fill CSR: bucket edges by dst, precompute coef ----------------
__global__ __launch_bounds__(256) void fill_k(const int* __restrict__ src,
                                              const int* __restrict__ dst,
                                              const float* __restrict__ dinv,
                                              int* __restrict__ cursor,
                                              int* __restrict__ csr_src,
                                              float* __restrict__ csr_coef) {
    int e = blockIdx.x * 256 + threadIdx.x;
    if (e >= N_EDGES) return;
    int s = src[e], d = dst[e];
    int pos = atomicAdd(&cursor[d], 1);
    csr_src[pos] = s;
    csr_coef[pos] = dinv[s] * dinv[d];
}

// ---------------- matmul: Y[nrows,128] = X[nrows,128] @ W[128,128] ----------------
__global__ __launch_bounds__(256) void matmul_k(const float* __restrict__ X,
                                                const float* __restrict__ W,
                                                float* __restrict__ Y,
                                                int nrows) {
    __shared__ float XsT[32][68];
    __shared__ float Ws[32][128];
    const int t = threadIdx.x;
    const int c8 = (t & 15) * 8;
    const int r4 = (t >> 4) * 4;
    const int row0 = blockIdx.x * 64;

    float acc[4][8];
#pragma unroll
    for (int i = 0; i < 4; ++i)
#pragma unroll
        for (int j = 0; j < 8; ++j) acc[i][j] = 0.f;

    for (int kp = 0; kp < 4; ++kp) {
        {
            const float4* Wp = (const float4*)(W + (size_t)kp * 32 * 128);
            float4* Wd = (float4*)(&Ws[0][0]);
#pragma unroll
            for (int i = 0; i < 4; ++i) Wd[t + i * 256] = Wp[t + i * 256];
        }
        {
#pragma unroll
            for (int i = 0; i < 8; ++i) {
                int idx = t + i * 256;
                int rr = idx >> 5;
                int kk = idx & 31;
                int grow = row0 + rr;
                float v = 0.f;
                if (grow < nrows) v = X[(size_t)grow * 128 + kp * 32 + kk];
                XsT[kk][rr] = v;
            }
        }
        __syncthreads();
#pragma unroll 8
        for (int kk = 0; kk < 32; ++kk) {
            float4 xv = *(const float4*)(&XsT[kk][r4]);
            float4 wa = *(const float4*)(&Ws[kk][c8]);
            float4 wb = *(const float4*)(&Ws[kk][c8 + 4]);
            float xs[4] = {xv.x, xv.y, xv.z, xv.w};
            float wv[8] = {wa.x, wa.y, wa.z, wa.w, wb.x, wb.y, wb.z, wb.w};
#pragma unroll
            for (int i = 0; i < 4; ++i)
#pragma unroll
                for (int j = 0; j < 8; ++j) acc[i][j] += xs[i] * wv[j];
        }
        __syncthreads();
    }
#pragma unroll
    for (int i = 0; i < 4; ++i) {
        int grow = row0 + r4 + i;
        if (grow < nrows) {
            float4* Yp = (float4*)(Y + (size_t)grow * 128 + c8);
            Yp[0] = make_float4(acc[i][0], acc[i][1], acc[i][2], acc[i][3]);
            Yp[1] = make_float4(acc[i][4], acc[i][5], acc[i][6], acc[i][7]);
        }
    }
}

// ---------------- gather: out[i] = sum_{e in CSR[i]} T[src_e]*coef_e + T[i]*dinv[i]^2 + b ----------------
// 32-lane group per node; 8-way unrolled edge loop for MLP (8 gathers in flight).
__global__ __launch_bounds__(256) void gather_k(const float* __restrict__ T,
                                                const int* __restrict__ rowptr,
                                                const int* __restrict__ csr_src,
                                                const float* __restrict__ csr_coef,
                                                const float* __restrict__ dinv,
                                                const float* __restrict__ b,
                                                float* __restrict__ out,
                                                int relu) {
    int i = blockIdx.x * 8 + (threadIdx.x >> 5);
    if (i >= N_NODES) return;
    const int j4 = (threadIdx.x & 31) * 4;
    const int beg = rowptr[i], end = rowptr[i + 1];

    float4 acc0 = make_float4(0.f, 0.f, 0.f, 0.f);
    float4 acc1 = make_float4(0.f, 0.f, 0.f, 0.f);
    int e = beg;
    for (; e + 7 < end; e += 8) {
        int   s0 = csr_src[e],     s1 = csr_src[e + 1], s2 = csr_src[e + 2], s3 = csr_src[e + 3];
        int   s4 = csr_src[e + 4], s5 = csr_src[e + 5], s6 = csr_src[e + 6], s7 = csr_src[e + 7];
        float c0 = csr_coef[e],     c1 = csr_coef[e + 1], c2 = csr_coef[e + 2], c3 = csr_coef[e + 3];
        float c4 = csr_coef[e + 4], c5 = csr_coef[e + 5], c6 = csr_coef[e + 6], c7 = csr_coef[e + 7];
        float4 v0 = *(const float4*)(T + (size_t)s0 * HD + j4);
        float4 v1 = *(const float4*)(T + (size_t)s1 * HD + j4);
        float4 v2 = *(const float4*)(T + (size_t)s2 * HD + j4);
        float4 v3 = *(const float4*)(T + (size_t)s3 * HD + j4);
        float4 v4 = *(const float4*)(T + (size_t)s4 * HD + j4);
        float4 v5 = *(const float4*)(T + (size_t)s5 * HD + j4);
        float4 v6 = *(const float4*)(T + (size_t)s6 * HD + j4);
        float4 v7 = *(const float4*)(T + (size_t)s7 * HD + j4);
        acc0.x += v0.x * c0 + v1.x * c1 + v2.x * c2 + v3.x * c3;
        acc0.y += v0.y * c0 + v1.y * c1 + v2.y * c2 + v3.y * c3;
        acc0.z += v0.z * c0 + v1.z * c1 + v2.z * c2 + v3.z * c3;
        acc0.w += v0.w * c0 + v1.w * c1 + v2.w * c2 + v3.w * c3;
        acc1.x += v4.x * c4 + v5.x * c5 + v6.x * c6 + v7.x * c7;
        acc1.y += v4.y * c4 + v5.y * c5 + v6.y * c6 + v7.y * c7;
        acc1.z += v4.z * c4 + v5.z * c5 + v6.z * c6 + v7.z * c7;
        acc1.w += v4.w * c4 + v5.w * c5 + v6.w * c6 + v7.w * c7;
    }
    for (; e + 3 < end; e += 4) {
        int s0 = csr_src[e], s1 = csr_src[e + 1], s2 = csr_src[e + 2], s3 = csr_src[e + 3];
        float c0 = csr_coef[e], c1 = csr_coef[e + 1], c2 = csr_coef[e + 2], c3 = csr_coef[e + 3];
        float4 v0 = *(const float4*)(T + (size_t)s0 * HD + j4);
        float4 v1 = *(const float4*)(T + (size_t)s1 * HD + j4);
        float4 v2 = *(const float4*)(T + (size_t)s2 * HD + j4);
        float4 v3 = *(const float4*)(T + (size_t)s3 * HD + j4);
        acc0.x += v0.x * c0 + v1.x * c1 + v2.x * c2 + v3.x * c3;
        acc0.y += v0.y * c0 + v1.y * c1 + v2.y * c2 + v3.y * c3;
        acc0.z += v0.z * c0 + v1.z * c1 + v2.z * c2 + v3.z * c3;
        acc0.w += v0.w * c0 + v1.w * c1 + v2.w * c2 + v3.w * c3;
    }
    for (; e < end; ++e) {
        int s = csr_src[e];
        float c = csr_coef[e];
        float4 v = *(const float4*)(T + (size_t)s * HD + j4);
        acc1.x += v.x * c; acc1.y += v.y * c; acc1.z += v.z * c; acc1.w += v.w * c;
    }
    float di = dinv[i];
    float sc = di * di;
    float4 tv = *(const float4*)(T + (size_t)i * HD + j4);
    float4 bv = *(const float4*)(b + j4);
    float4 r;
    r.x = acc0.x + acc1.x + tv.x * sc + bv.x;
    r.y = acc0.y + acc1.y + tv.y * sc + bv.y;
    r.z = acc0.z + acc1.z + tv.z * sc + bv.z;
    r.w = acc0.w + acc1.w + tv.w * sc + bv.w;
    if (relu) {
        r.x = fmaxf(r.x, 0.f); r.y = fmaxf(r.y, 0.f);
        r.z = fmaxf(r.z, 0.f); r.w = fmaxf(r.w, 0.f);
    }
    *(float4*)(out + (size_t)i * HD + j4) = r;
}

// ---------------- global mean pool: run-length segmented reduction over sorted batch ----------------
__global__ __launch_bounds__(256) void pool2_k(const float* __restrict__ H2,
                                               const int* __restrict__ batch,
                                               float* __restrict__ sums,
                                               float* __restrict__ cnt) {
    const int t = threadIdx.x;
    const int f = t & 127;
    const int half = t >> 7;
    int i0 = blockIdx.x * 128 + half * 64;
    if (i0 >= N_NODES) return;
    int i1 = i0 + 64; if (i1 > N_NODES) i1 = N_NODES;

    int cur = batch[i0];
    float acc = 0.f;
    float c = 0.f;
    for (int i = i0; i < i1; ++i) {
        int g = batch[i];
        if (g != cur) {
            atomicAdd(&sums[cur * HD + f], acc);
            if (f == 0) atomicAdd(&cnt[cur], c);
            acc = 0.f; c = 0.f; cur = g;
        }
        acc += H2[(size_t)i * HD + f];
        c += 1.f;
    }
    atomicAdd(&sums[cur * HD + f], acc);
    if (f == 0) atomicAdd(&cnt[cur], c);
}

// ---------------- head ----------------
__global__ __launch_bounds__(512) void head_k(const float* __restrict__ sums,
                                              const float* __restrict__ cnt,
                                              const float* __restrict__ Wh,
                                              const float* __restrict__ bh,
                                              float* __restrict__ out) {
    int t = threadIdx.x;
    int g = t >> 3, o = t & 7;
    float inv = 1.0f / fmaxf(cnt[g], 1.0f);
    float acc = bh[o];
    for (int h = 0; h < HD; ++h)
        acc += sums[g * HD + h] * inv * Wh[h * NOUT + o];
    out[g * NOUT + o] = acc;
}

extern "C" void kernel_launch(void* const* d_in, const int* in_sizes, int n_in,
                              void* d_out, int out_size, void* d_ws, size_t ws_size,
                              hipStream_t stream) {
    const float* x  = (const float*)d_in[0];
    const int*   ei = (const int*)d_in[1];
    const int*   batch = (const int*)d_in[2];
    const float* W0 = (const float*)d_in[3];
    const float* b0 = (const float*)d_in[4];
    const float* W1 = (const float*)d_in[5];
    const float* b1 = (const float*)d_in[6];
    const float* W2 = (const float*)d_in[7];
    const float* b2 = (const float*)d_in[8];
    const float* Wh = (const float*)d_in[9];
    const float* bh = (const float*)d_in[10];
    float* out = (float*)d_out;

    const int* src = ei;
    const int* dst = ei + N_EDGES;

    char* wsb = (char*)d_ws;
    int*   deg      = (int*)(wsb + 0);                          // N
    float* dinv     = (float*)(wsb + 200000);                   // N
    int*   rowptr   = (int*)(wsb + 400000);                     // N+1
    int*   cursor   = (int*)(wsb + 600016);                     // N
    int*   csr_src  = (int*)(wsb + 800016);                     // E
    float* csr_coef = (float*)(wsb + 4000016);                  // E
    float* A        = (float*)(wsb + 7200016);                  // N*HD
    float* B        = (float*)(wsb + 32800016);                 // N*HD
    float* sums     = (float*)(wsb + 58400016);                 // G*HD
    float* cnt      = (float*)(wsb + 58432784);                 // G
    int*   part     = (int*)(wsb + 58433056);                   // SCAN_BLOCKS
    int*   partoff  = (int*)(wsb + 58433568);                   // SCAN_BLOCKS

    const int mmGrid = (N_NODES + 63) / 64;
    const int gaGrid = (N_NODES + 7) / 8;

    // ---- CSR build ----
    hipMemsetAsync(deg, 0, N_NODES * sizeof(int), stream);
    deg_k<<<(N_EDGES + 255) / 256, 256, 0, stream>>>(dst, deg);
    dinv_k<<<(N_NODES + 255) / 256, 256, 0, stream>>>(deg, dinv);
    part_k<<<SCAN_BLOCKS, 256, 0, stream>>>(deg, part);
    scanpart_k<<<1, 128, 0, stream>>>(part, partoff, rowptr);
    rowfill_k<<<SCAN_BLOCKS, 256, 0, stream>>>(deg, partoff, rowptr, cursor);
    fill_k<<<(N_EDGES + 255) / 256, 256, 0, stream>>>(src, dst, dinv, cursor, csr_src, csr_coef);

    // ---- layer 0 ----
    matmul_k<<<mmGrid, 256, 0, stream>>>(x, W0, A, N_NODES);
    gather_k<<<gaGrid, 256, 0, stream>>>(A, rowptr, csr_src, csr_coef, dinv, b0, B, 1);

    // ---- layer 1 ----
    matmul_k<<<mmGrid, 256, 0, stream>>>(B, W1, A, N_NODES);
    gather_k<<<gaGrid, 256, 0, stream>>>(A, rowptr, csr_src, csr_coef, dinv, b1, B, 1);

    // ---- layer 2 (no relu) ----
    matmul_k<<<mmGrid, 256, 0, stream>>>(B, W2, A, N_NODES);
    gather_k<<<gaGrid, 256, 0, stream>>>(A, rowptr, csr_src, csr_coef, dinv, b2, B, 0);

    // ---- pool + head ----
    hipMemsetAsync(sums, 0, (NGRAPH * HD + NGRAPH) * sizeof(float), stream);
    pool2_k<<<(N_NODES + 127) / 128, 256, 0, stream>>>(B, batch, sums, cnt);
    head_k<<<1, 512, 0, stream>>>(sums, cnt, Wh, bh, out);
}

// Round 5
// 395.363 us; speedup vs baseline: 11.9991x; 1.3426x over previous
//
#include <hip/hip_runtime.h>

#define N_NODES 50000
#define N_EDGES 800000
#define HD 128
#define NGRAPH 64
#define NOUT 8

#define SCAN_CHUNK 512
#define SCAN_BLOCKS ((N_NODES + SCAN_CHUNK - 1) / SCAN_CHUNK)   // 98

typedef __attribute__((ext_vector_type(8))) short bf8_t;
typedef __attribute__((ext_vector_type(4))) float f4_t;

__device__ __forceinline__ unsigned short f2b(float f) {   // fp32 -> bf16 RNE
    unsigned u = __float_as_uint(f);
    u += 0x7fffu + ((u >> 16) & 1u);
    return (unsigned short)(u >> 16);
}
__device__ __forceinline__ float b2f(unsigned short h) {
    return __uint_as_float(((unsigned)h) << 16);
}

// ---------------- degree (int) ----------------
__global__ __launch_bounds__(256) void deg_k(const int* __restrict__ dst, int* __restrict__ deg) {
    int e = blockIdx.x * 256 + threadIdx.x;
    if (e < N_EDGES) atomicAdd(&deg[dst[e]], 1);
}

__global__ __launch_bounds__(256) void dinv_k(const int* __restrict__ deg, float* __restrict__ dinv) {
    int i = blockIdx.x * 256 + threadIdx.x;
    if (i < N_NODES) dinv[i] = 1.0f / sqrtf((float)deg[i] + 1.0f);
}

// ---------------- two-level scan ----------------
__global__ __launch_bounds__(256) void part_k(const int* __restrict__ deg, int* __restrict__ part) {
    __shared__ int red[256];
    const int t = threadIdx.x;
    int i0 = blockIdx.x * SCAN_CHUNK + 2 * t;
    int s = 0;
    if (i0 < N_NODES) s += deg[i0];
    if (i0 + 1 < N_NODES) s += deg[i0 + 1];
    red[t] = s;
    __syncthreads();
    for (int off = 128; off > 0; off >>= 1) {
        if (t < off) red[t] += red[t + off];
        __syncthreads();
    }
    if (t == 0) part[blockIdx.x] = red[0];
}

__global__ __launch_bounds__(128) void scanpart_k(const int* __restrict__ part,
                                                  int* __restrict__ partoff,
                                                  int* __restrict__ rowptr) {
    __shared__ int sh[128];
    const int t = threadIdx.x;
    int v = (t < SCAN_BLOCKS) ? part[t] : 0;
    sh[t] = v;
    for (int off = 1; off < 128; off <<= 1) {
        __syncthreads();
        int u = (t >= off) ? sh[t - off] : 0;
        __syncthreads();
        sh[t] += u;
    }
    __syncthreads();
    if (t < SCAN_BLOCKS) partoff[t] = sh[t] - v;
    if (t == 0) rowptr[N_NODES] = N_EDGES;
}

__global__ __launch_bounds__(256) void rowfill_k(const int* __restrict__ deg,
                                                 const int* __restrict__ partoff,
                                                 int* __restrict__ rowptr,
                                                 int* __restrict__ cursor) {
    __shared__ int sh[256];
    const int t = threadIdx.x;
    int i0 = blockIdx.x * SCAN_CHUNK + 2 * t;
    int d0 = (i0 < N_NODES) ? deg[i0] : 0;
    int d1 = (i0 + 1 < N_NODES) ? deg[i0 + 1] : 0;
    int s = d0 + d1;
    sh[t] = s;
    for (int off = 1; off < 256; off <<= 1) {
        __syncthreads();
        int u = (t >= off) ? sh[t - off] : 0;
        __syncthreads();
        sh[t] += u;
    }
    __syncthreads();
    int p = partoff[blockIdx.x] + sh[t] - s;
    if (i0 < N_NODES)     { rowptr[i0] = p;          cursor[i0] = p; }
    if (i0 + 1 < N_NODES) { rowptr[i0 + 1] = p + d0; cursor[i0 + 1] = p + d0; }
}

// ---------------- fill CSR ----------------
__global__ __launch_bounds__(256) void fill_k(const int* __restrict__ src,
                                              const int* __restrict__ dst,
                                              const float* __restrict__ dinv,
                                              int* __restrict__ cursor,
                                              int* __restrict__ csr_src,
                                              float* __restrict__ csr_coef) {
    int e = blockIdx.x * 256 + threadIdx.x;
    if (e >= N_EDGES) return;
    int s = src[e], d = dst[e];
    int pos = atomicAdd(&cursor[d], 1);
    csr_src[pos] = s;
    csr_coef[pos] = dinv[s] * dinv[d];
}

// ---------------- convert x -> bf16 ----------------
__global__ __launch_bounds__(256) void cvtx_k(const float* __restrict__ x, unsigned short* __restrict__ xh) {
    int i = blockIdx.x * 256 + threadIdx.x;          // float4 index
    const int n4 = N_NODES * HD / 4;
    if (i >= n4) return;
    float4 v = *(const float4*)(x + (size_t)i * 4);
    ushort4 o;
    o.x = f2b(v.x); o.y = f2b(v.y); o.z = f2b(v.z); o.w = f2b(v.w);
    *(ushort4*)(xh + (size_t)i * 4) = o;
}

// ---------------- convert+transpose W[128,128] (k,n) -> WT[n,k] bf16, 3 mats ----------------
__global__ __launch_bounds__(256) void cvtw_k(const float* __restrict__ W0,
                                              const float* __restrict__ W1,
                                              const float* __restrict__ W2,
                                              unsigned short* __restrict__ WT) {
    int idx = blockIdx.x * 256 + threadIdx.x;
    if (idx >= 3 * HD * HD) return;
    int w = idx >> 14;
    int rem = idx & 16383;
    int n = rem >> 7;
    int k = rem & 127;
    const float* W = (w == 0) ? W0 : (w == 1) ? W1 : W2;
    WT[(size_t)w * HD * HD + n * HD + k] = f2b(W[k * HD + n]);
}

// ---------------- MFMA matmul: Y[N,128](bf16) = X[N,128](bf16) @ W (via WT[n,k] bf16) ----------------
// 256 thr = 4 waves; wave handles 16 rows x 128 cols; K=128 in 4 chunks of 32.
__global__ __launch_bounds__(256) void mm_bf16_k(const unsigned short* __restrict__ X,
                                                 const unsigned short* __restrict__ WT,
                                                 unsigned short* __restrict__ Y) {
    const int lane = threadIdx.x & 63;
    const int wave = threadIdx.x >> 6;
    const int r = lane & 15;
    const int q = lane >> 4;
    const int row0 = blockIdx.x * 64 + wave * 16;
    int arow = row0 + r; if (arow >= N_NODES) arow = N_NODES - 1;

    f4_t acc[8];
#pragma unroll
    for (int n = 0; n < 8; ++n) acc[n] = (f4_t){0.f, 0.f, 0.f, 0.f};

#pragma unroll
    for (int kb = 0; kb < 4; ++kb) {
        bf8_t a = *(const bf8_t*)(X + (size_t)arow * HD + kb * 32 + q * 8);
#pragma unroll
        for (int n = 0; n < 8; ++n) {
            bf8_t b = *(const bf8_t*)(WT + (size_t)(n * 16 + r) * HD + kb * 32 + q * 8);
            acc[n] = __builtin_amdgcn_mfma_f32_16x16x32_bf16(a, b, acc[n], 0, 0, 0);
        }
    }
    const int orow = row0 + q * 4;
#pragma unroll
    for (int n = 0; n < 8; ++n) {
#pragma unroll
        for (int i = 0; i < 4; ++i) {
            int rr = orow + i;
            if (rr < N_NODES) Y[(size_t)rr * HD + n * 16 + r] = f2b(acc[n][i]);
        }
    }
}

// ---------------- gather (bf16 in/out, fp32 accumulate) ----------------
__global__ __launch_bounds__(256) void gather_k(const unsigned short* __restrict__ T,
                                                const int* __restrict__ rowptr,
                                                const int* __restrict__ csr_src,
                                                const float* __restrict__ csr_coef,
                                                const float* __restrict__ dinv,
                                                const float* __restrict__ b,
                                                unsigned short* __restrict__ out,
                                                int relu) {
    int i = blockIdx.x * 8 + (threadIdx.x >> 5);
    if (i >= N_NODES) return;
    const int j4 = (threadIdx.x & 31) * 4;
    const int beg = rowptr[i], end = rowptr[i + 1];

    float ax = 0.f, ay = 0.f, az = 0.f, aw = 0.f;
    float bx = 0.f, by = 0.f, bz = 0.f, bw = 0.f;
    int e = beg;
    for (; e + 7 < end; e += 8) {
        int   s0 = csr_src[e],     s1 = csr_src[e + 1], s2 = csr_src[e + 2], s3 = csr_src[e + 3];
        int   s4 = csr_src[e + 4], s5 = csr_src[e + 5], s6 = csr_src[e + 6], s7 = csr_src[e + 7];
        float c0 = csr_coef[e],     c1 = csr_coef[e + 1], c2 = csr_coef[e + 2], c3 = csr_coef[e + 3];
        float c4 = csr_coef[e + 4], c5 = csr_coef[e + 5], c6 = csr_coef[e + 6], c7 = csr_coef[e + 7];
        ushort4 v0 = *(const ushort4*)(T + (size_t)s0 * HD + j4);
        ushort4 v1 = *(const ushort4*)(T + (size_t)s1 * HD + j4);
        ushort4 v2 = *(const ushort4*)(T + (size_t)s2 * HD + j4);
        ushort4 v3 = *(const ushort4*)(T + (size_t)s3 * HD + j4);
        ushort4 v4 = *(const ushort4*)(T + (size_t)s4 * HD + j4);
        ushort4 v5 = *(const ushort4*)(T + (size_t)s5 * HD + j4);
        ushort4 v6 = *(const ushort4*)(T + (size_t)s6 * HD + j4);
        ushort4 v7 = *(const ushort4*)(T + (size_t)s7 * HD + j4);
        ax += b2f(v0.x) * c0 + b2f(v1.x) * c1 + b2f(v2.x) * c2 + b2f(v3.x) * c3;
        ay += b2f(v0.y) * c0 + b2f(v1.y) * c1 + b2f(v2.y) * c2 + b2f(v3.y) * c3;
        az += b2f(v0.z) * c0 + b2f(v1.z) * c1 + b2f(v2.z) * c2 + b2f(v3.z) * c3;
        aw += b2f(v0.w) * c0 + b2f(v1.w) * c1 + b2f(v2.w) * c2 + b2f(v3.w) * c3;
        bx += b2f(v4.x) * c4 + b2f(v5.x) * c5 + b2f(v6.x) * c6 + b2f(v7.x) * c7;
        by += b2f(v4.y) * c4 + b2f(v5.y) * c5 + b2f(v6.y) * c6 + b2f(v7.y) * c7;
        bz += b2f(v4.z) * c4 + b2f(v5.z) * c5 + b2f(v6.z) * c6 + b2f(v7.z) * c7;
        bw += b2f(v4.w) * c4 + b2f(v5.w) * c5 + b2f(v6.w) * c6 + b2f(v7.w) * c7;
    }
    for (; e < end; ++e) {
        int s = csr_src[e];
        float c = csr_coef[e];
        ushort4 v = *(const ushort4*)(T + (size_t)s * HD + j4);
        ax += b2f(v.x) * c; ay += b2f(v.y) * c; az += b2f(v.z) * c; aw += b2f(v.w) * c;
    }
    float di = dinv[i];
    float sc = di * di;
    ushort4 tv = *(const ushort4*)(T + (size_t)i * HD + j4);
    const float4 bv = *(const float4*)(b + j4);
    float rx = ax + bx + b2f(tv.x) * sc + bv.x;
    float ry = ay + by + b2f(tv.y) * sc + bv.y;
    float rz = az + bz + b2f(tv.z) * sc + bv.z;
    float rw = aw + bw + b2f(tv.w) * sc + bv.w;
    if (relu) {
        rx = fmaxf(rx, 0.f); ry = fmaxf(ry, 0.f);
        rz = fmaxf(rz, 0.f); rw = fmaxf(rw, 0.f);
    }
    ushort4 o;
    o.x = f2b(rx); o.y = f2b(ry); o.z = f2b(rz); o.w = f2b(rw);
    *(ushort4*)(out + (size_t)i * HD + j4) = o;
}

// ---------------- global mean pool over sorted batch (bf16 input, fp32 sums) ----------------
__global__ __launch_bounds__(256) void pool2_k(const unsigned short* __restrict__ H2,
                                               const int* __restrict__ batch,
                                               float* __restrict__ sums,
                                               float* __restrict__ cnt) {
    const int t = threadIdx.x;
    const int f = t & 127;
    const int half = t >> 7;
    int i0 = blockIdx.x * 128 + half * 64;
    if (i0 >= N_NODES) return;
    int i1 = i0 + 64; if (i1 > N_NODES) i1 = N_NODES;

    int cur = batch[i0];
    float acc = 0.f;
    float c = 0.f;
    for (int i = i0; i < i1; ++i) {
        int g = batch[i];
        if (g != cur) {
            atomicAdd(&sums[cur * HD + f], acc);
            if (f == 0) atomicAdd(&cnt[cur], c);
            acc = 0.f; c = 0.f; cur = g;
        }
        acc += b2f(H2[(size_t)i * HD + f]);
        c += 1.f;
    }
    atomicAdd(&sums[cur * HD + f], acc);
    if (f == 0) atomicAdd(&cnt[cur], c);
}

// ---------------- head (fp32) ----------------
__global__ __launch_bounds__(512) void head_k(const float* __restrict__ sums,
                                              const float* __restrict__ cnt,
                                              const float* __restrict__ Wh,
                                              const float* __restrict__ bh,
                                              float* __restrict__ out) {
    int t = threadIdx.x;
    int g = t >> 3, o = t & 7;
    float inv = 1.0f / fmaxf(cnt[g], 1.0f);
    float acc = bh[o];
    for (int h = 0; h < HD; ++h)
        acc += sums[g * HD + h] * inv * Wh[h * NOUT + o];
    out[g * NOUT + o] = acc;
}

extern "C" void kernel_launch(void* const* d_in, const int* in_sizes, int n_in,
                              void* d_out, int out_size, void* d_ws, size_t ws_size,
                              hipStream_t stream) {
    const float* x  = (const float*)d_in[0];
    const int*   ei = (const int*)d_in[1];
    const int*   batch = (const int*)d_in[2];
    const float* W0 = (const float*)d_in[3];
    const float* b0 = (const float*)d_in[4];
    const float* W1 = (const float*)d_in[5];
    const float* b1 = (const float*)d_in[6];
    const float* W2 = (const float*)d_in[7];
    const float* b2 = (const float*)d_in[8];
    const float* Wh = (const float*)d_in[9];
    const float* bh = (const float*)d_in[10];
    float* out = (float*)d_out;

    const int* src = ei;
    const int* dst = ei + N_EDGES;

    char* wsb = (char*)d_ws;
    int*            deg      = (int*)(wsb + 0);            // N
    float*          dinv     = (float*)(wsb + 200000);     // N
    int*            rowptr   = (int*)(wsb + 400000);       // N+1
    int*            cursor   = (int*)(wsb + 600016);       // N
    int*            csr_src  = (int*)(wsb + 800016);       // E
    float*          csr_coef = (float*)(wsb + 4000016);    // E
    int*            part     = (int*)(wsb + 7200016);      // 98
    int*            partoff  = (int*)(wsb + 7200528);      // 98
    unsigned short* xh       = (unsigned short*)(wsb + 7201024);   // N*HD bf16
    unsigned short* WT       = (unsigned short*)(wsb + 20001024);  // 3*HD*HD bf16
    unsigned short* A        = (unsigned short*)(wsb + 20099328);  // N*HD bf16
    unsigned short* B        = (unsigned short*)(wsb + 32899328);  // N*HD bf16
    float*          sums     = (float*)(wsb + 45699328);   // G*HD
    float*          cnt      = (float*)(wsb + 45732096);   // G

    const int mmGrid = (N_NODES + 63) / 64;
    const int gaGrid = (N_NODES + 7) / 8;

    // ---- CSR build + conversions ----
    hipMemsetAsync(deg, 0, N_NODES * sizeof(int), stream);
    deg_k<<<(N_EDGES + 255) / 256, 256, 0, stream>>>(dst, deg);
    dinv_k<<<(N_NODES + 255) / 256, 256, 0, stream>>>(deg, dinv);
    part_k<<<SCAN_BLOCKS, 256, 0, stream>>>(deg, part);
    scanpart_k<<<1, 128, 0, stream>>>(part, partoff, rowptr);
    rowfill_k<<<SCAN_BLOCKS, 256, 0, stream>>>(deg, partoff, rowptr, cursor);
    fill_k<<<(N_EDGES + 255) / 256, 256, 0, stream>>>(src, dst, dinv, cursor, csr_src, csr_coef);
    cvtx_k<<<(N_NODES * HD / 4 + 255) / 256, 256, 0, stream>>>(x, xh);
    cvtw_k<<<(3 * HD * HD + 255) / 256, 256, 0, stream>>>(W0, W1, W2, WT);

    // ---- layer 0 ----
    mm_bf16_k<<<mmGrid, 256, 0, stream>>>(xh, WT, A);
    gather_k<<<gaGrid, 256, 0, stream>>>(A, rowptr, csr_src, csr_coef, dinv, b0, B, 1);

    // ---- layer 1 ----
    mm_bf16_k<<<mmGrid, 256, 0, stream>>>(B, WT + HD * HD, A);
    gather_k<<<gaGrid, 256, 0, stream>>>(A, rowptr, csr_src, csr_coef, dinv, b1, B, 1);

    // ---- layer 2 (no relu) ----
    mm_bf16_k<<<mmGrid, 256, 0, stream>>>(B, WT + 2 * HD * HD, A);
    gather_k<<<gaGrid, 256, 0, stream>>>(A, rowptr, csr_src, csr_coef, dinv, b2, B, 0);

    // ---- pool + head ----
    hipMemsetAsync(sums, 0, (NGRAPH * HD + NGRAPH) * sizeof(float), stream);
    pool2_k<<<(N_NODES + 127) / 128, 256, 0, stream>>>(B, batch, sums, cnt);
    head_k<<<1, 512, 0, stream>>>(sums, cnt, Wh, bh, out);
}